// Round 18
// baseline (188.712 us; speedup 1.0000x reference)
//
#include <hip/hip_runtime.h>
#include <hip/hip_bf16.h>
#include <stdint.h>

typedef unsigned short u16;
typedef uint32_t u32;
typedef __attribute__((ext_vector_type(4))) float f32x4;
typedef __attribute__((ext_vector_type(16))) float f32x16;
typedef __attribute__((ext_vector_type(8))) short s8v;     // 8 bf16 as shorts (4 VGPR)
typedef __attribute__((ext_vector_type(4))) unsigned short u16x4;
typedef __attribute__((ext_vector_type(2))) uint32_t u32x2;
typedef __attribute__((ext_vector_type(4))) uint32_t u32x4;

#define SCALE_Q 0.18033688f   // (1/8) * log2(e): scores come out in log2 domain

union PU { s8v v; u32 w[4]; };

__device__ __forceinline__ u16 f2bf(float f) {
  union { float f; uint32_t u; } v; v.f = f;
  uint32_t r = v.u + 0x7fffu + ((v.u >> 16) & 1u);   // RNE, no NaN inputs
  return (u16)(r >> 16);
}

__device__ __forceinline__ u32 pk2(float lo, float hi) {
  __hip_bfloat162 h = __float22bfloat162_rn(float2{lo, hi});
  union { __hip_bfloat162 h; u32 u; } c; c.h = h; return c.u;
}

// async global->LDS, 16B per lane; LDS base is WAVE-UNIFORM (HW adds lane*16)
__device__ __forceinline__ void gl16(const void* g, void* l) {
  __builtin_amdgcn_global_load_lds((const __attribute__((address_space(1))) u32*)g,
                                   (__attribute__((address_space(3))) u32*)l, 16, 0, 0);
}

#define BARRIER()  __builtin_amdgcn_s_barrier()
#define SCHEDB()   __builtin_amdgcn_sched_barrier(0)
#define SGB(m, n)  __builtin_amdgcn_sched_group_barrier((m), (n), 0)
#define MEMPIN()   asm volatile("" ::: "memory")   // pin VMEM issue order (counted-vmcnt rule)

// Merged weight transposes (one launch):
//  z=0..2: W[h][d][kk] f32 -> WT[n=h*64+kk][d] bf16 (q-slice folds SCALE_Q)
//  z=3   : Wo[k][n]   f32 -> WoT[n][k] bf16
__global__ __launch_bounds__(256) void k_convW_all(const float* __restrict__ wq, const float* __restrict__ wk,
                                                   const float* __restrict__ wv, const float* __restrict__ wo,
                                                   u16* __restrict__ oq, u16* __restrict__ ok,
                                                   u16* __restrict__ ov, u16* __restrict__ oo) {
  __shared__ float T[64][65];
  const int z = blockIdx.z;
  const int t = threadIdx.x;
  if (z < 3) {
    const int h = blockIdx.y, d0 = blockIdx.x * 64;
    const float* w = z == 0 ? wq : (z == 1 ? wk : wv);
    u16* o = z == 0 ? oq : (z == 1 ? ok : ov);
    const float scale = z == 0 ? SCALE_Q : 1.0f;
#pragma unroll
    for (int i = 0; i < 16; ++i) {
      int f = t + i * 256;
      T[f >> 6][f & 63] = w[(h * 1024 + d0 + (f >> 6)) * 64 + (f & 63)];
    }
    __syncthreads();
#pragma unroll
    for (int i = 0; i < 16; ++i) {
      int g = t + i * 256;
      o[(h * 64 + (g >> 6)) * 1024 + d0 + (g & 63)] = f2bf(T[g & 63][g >> 6] * scale);
    }
  } else {
    const int n0 = blockIdx.x * 64, c0 = blockIdx.y * 64;
#pragma unroll
    for (int i = 0; i < 16; ++i) {
      int f = t + i * 256;
      T[f >> 6][f & 63] = wo[(c0 + (f >> 6)) * 1024 + n0 + (f & 63)];
    }
    __syncthreads();
#pragma unroll
    for (int i = 0; i < 16; ++i) {
      int g = t + i * 256;
      oo[(n0 + (g >> 6)) * 1024 + c0 + (g & 63)] = f2bf(T[g & 63][g >> 6]);
    }
  }
}

// ---------- fused conv+QKV projection GEMM: A is f32, converted during reg-staging ----------
// Counted-vmcnt rule: BSTG's 4 gl16 and ALOAD's 8 global loads are fenced with MEMPIN()
// so issue order is guaranteed 4xgl16 then 8xload -> vmcnt(8) retires exactly the gl16s.
__global__ __launch_bounds__(256) void k_gemm3f(
    const float* __restrict__ Aq, const float* __restrict__ Ak, const float* __restrict__ Av,
    const u16* __restrict__ Bq, const u16* __restrict__ Bk, const u16* __restrict__ Bv,
    const float* __restrict__ bqp, const float* __restrict__ bkp, const float* __restrict__ bvp,
    u16* __restrict__ oq, u16* __restrict__ ok, u16* __restrict__ ov) {
  constexpr int Kd = 1024, Nd = 1024;
  __shared__ alignas(16) u16 As[128 * 64];
  __shared__ alignas(16) u16 Bs[128 * 64];
  const int z = blockIdx.z;
  const float* A = z == 0 ? Aq : (z == 1 ? Ak : Av);
  const u16* Bt = z == 0 ? Bq : (z == 1 ? Bk : Bv);
  const float* bias = z == 0 ? bqp : (z == 1 ? bkp : bvp);

  const int t = threadIdx.x;
  const int lane = t & 63;
  const int w = t >> 6;
  const int wm = w >> 1, wn = w & 1;
  const int lr = lane & 15, lg = lane >> 4;
  const long bm = blockIdx.x * 128, bn = blockIdx.y * 128;
  const int r8 = lane >> 3, c8 = lane & 7;
  const int chunk = c8 ^ r8;               // B pre-swizzled source chunk

  // A reg-stage: thread t owns rows {arow_s + 32j, j=0..3}, chunk achk (8 f32 wide)
  const int arow_s = t >> 3, achk = t & 7;
  const int aswz = (achk ^ (arow_s & 7)) * 8;      // row&7 == arow_s&7 for all j
  const float* Apf = A + (bm + arow_s) * (long)Kd + achk * 8;
  const u16* Bp = Bt + (bn + w * 8 + r8) * (long)Kd + chunk * 8;

  f32x4 acc[4][4] = {};
  float4 fa[4][2];

  auto ALOAD = [&](int kt) {
#pragma unroll
    for (int j = 0; j < 4; ++j) {
      fa[j][0] = *(const float4*)(Apf + (long)j * 32 * Kd + kt);
      fa[j][1] = *(const float4*)(Apf + (long)j * 32 * Kd + kt + 4);
    }
  };
  auto AWRITE = [&]() {
#pragma unroll
    for (int j = 0; j < 4; ++j) {
      u32x4 pk;
      pk[0] = pk2(fa[j][0].x, fa[j][0].y);
      pk[1] = pk2(fa[j][0].z, fa[j][0].w);
      pk[2] = pk2(fa[j][1].x, fa[j][1].y);
      pk[3] = pk2(fa[j][1].z, fa[j][1].w);
      *(u32x4*)(&As[(j * 32 + arow_s) * 64 + aswz]) = pk;
    }
  };
  auto BSTG = [&](int kt) {
#pragma unroll
    for (int p = 0; p < 4; ++p)
      gl16(Bp + (long)p * 32 * Kd + kt, Bs + (p * 32 + w * 8) * 64);
  };
  auto GCOMP = [&]() {
#pragma unroll
    for (int ks = 0; ks < 2; ++ks) {
      s8v af[4], bf[4];
#pragma unroll
      for (int i = 0; i < 4; ++i) {
        int arow = wm * 64 + i * 16 + lr;
        af[i] = *(const s8v*)(&As[arow * 64 + (((ks * 4 + lg) ^ (arow & 7)) * 8)]);
        int brow = wn * 64 + i * 16 + lr;
        bf[i] = *(const s8v*)(&Bs[brow * 64 + (((ks * 4 + lg) ^ (brow & 7)) * 8)]);
      }
#pragma unroll
      for (int i = 0; i < 4; ++i)
#pragma unroll
        for (int j = 0; j < 4; ++j)
          acc[i][j] = __builtin_amdgcn_mfma_f32_16x16x32_bf16(af[i], bf[j], acc[i][j], 0, 0, 0);
    }
  };

  ALOAD(0);
  for (int kt = 0; kt < 16; ++kt) {
    BARRIER();                             // all waves done reading As/Bs (prev compute)
    SCHEDB();
    AWRITE();                              // consumes fa (compiler waits on A-loads here)
    MEMPIN();
    BSTG(kt * 64);                         // 4x gl16 issued...
    MEMPIN();                              // ...strictly BEFORE the 8 A-loads below
    if (kt < 15) {
      ALOAD((kt + 1) * 64);                // in flight across next compute
      MEMPIN();
      asm volatile("s_waitcnt vmcnt(8) lgkmcnt(0)" ::: "memory");  // retires exactly the 4 gl16 + ds_writes
    } else {
      asm volatile("s_waitcnt vmcnt(0) lgkmcnt(0)" ::: "memory");
    }
    SCHEDB();
    BARRIER();                             // tile staged everywhere
    SCHEDB();
    GCOMP();
  }

  const float bscale = z == 0 ? SCALE_Q : 1.0f;
  float bcol[4];
#pragma unroll
  for (int j = 0; j < 4; ++j) bcol[j] = bias[bn + wn * 64 + j * 16 + lr] * bscale;

  if (z < 2) {
    u16* C = z == 0 ? oq : ok;
#pragma unroll
    for (int i = 0; i < 4; ++i) {
      long m0 = bm + wm * 64 + i * 16 + lg * 4;
#pragma unroll
      for (int j = 0; j < 4; ++j) {
        long n = bn + wn * 64 + j * 16 + lr;
#pragma unroll
        for (int r = 0; r < 4; ++r)
          C[(m0 + r) * Nd + n] = f2bf(acc[i][j][r] + bcol[j]);
      }
    }
  } else {
    // V out, transposed vT[((b*16+h)*64+dv)][2048] with kv-axis pi-permutation
    // (bits 3<->2 of the within-16 s offset) so PV's B-frag is lane-local in k_attn.
    u16* C = ov;
    int lgp = ((lg & 1) << 1) | (lg >> 1);
#pragma unroll
    for (int i = 0; i < 4; ++i) {
      long m0 = bm + wm * 64 + i * 16 + lgp * 4;
      int b = (int)(m0 >> 11), s0 = (int)(m0 & 2047);
#pragma unroll
      for (int j = 0; j < 4; ++j) {
        int n = (int)(bn + wn * 64 + j * 16 + lr);
        int h = n >> 6, dv = n & 63;
        u32x2 cc;
        cc[0] = pk2(acc[i][j][0] + bcol[j], acc[i][j][1] + bcol[j]);
        cc[1] = pk2(acc[i][j][2] + bcol[j], acc[i][j][3] + bcol[j]);
        *(u32x2*)(C + (long)((b * 16 + h) * 64 + dv) * 2048 + s0) = cc;
      }
    }
  }
}

// ---------- output projection GEMM (bf16 in, f32 out), counted-vmcnt pipeline ----------
__global__ __launch_bounds__(256) void k_gemmo(const u16* __restrict__ A, const u16* __restrict__ Bt,
                                               const float* __restrict__ bias, float* __restrict__ C) {
  constexpr int Kd = 1024, Nd = 1024;
  __shared__ alignas(16) u16 As[2][128 * 64];
  __shared__ alignas(16) u16 Bs[2][128 * 64];
  const int t = threadIdx.x;
  const int lane = t & 63;
  const int w = t >> 6;
  const int wm = w >> 1, wn = w & 1;
  const int lr = lane & 15, lg = lane >> 4;
  const long bm = blockIdx.x * 128, bn = blockIdx.y * 128;
  const int r8 = lane >> 3, c8 = lane & 7;
  const int chunk = c8 ^ r8;

  f32x4 acc[4][4] = {};
  const u16* Ap = A + (bm + w * 8 + r8) * (long)Kd + chunk * 8;
  const u16* Bp = Bt + (bn + w * 8 + r8) * (long)Kd + chunk * 8;

  auto GSTAGE = [&](u16* Asb, u16* Bsb, int kt) {
#pragma unroll
    for (int p = 0; p < 4; ++p) {
      gl16(Ap + (long)p * 32 * Kd + kt, Asb + (p * 32 + w * 8) * 64);
      gl16(Bp + (long)p * 32 * Kd + kt, Bsb + (p * 32 + w * 8) * 64);
    }
  };
  auto GCOMP = [&](const u16* Asb, const u16* Bsb) {
#pragma unroll
    for (int ks = 0; ks < 2; ++ks) {
      s8v af[4], bf[4];
#pragma unroll
      for (int i = 0; i < 4; ++i) {
        int arow = wm * 64 + i * 16 + lr;
        af[i] = *(const s8v*)(Asb + arow * 64 + (((ks * 4 + lg) ^ (arow & 7)) * 8));
        int brow = wn * 64 + i * 16 + lr;
        bf[i] = *(const s8v*)(Bsb + brow * 64 + (((ks * 4 + lg) ^ (brow & 7)) * 8));
      }
#pragma unroll
      for (int i = 0; i < 4; ++i)
#pragma unroll
        for (int j = 0; j < 4; ++j)
          acc[i][j] = __builtin_amdgcn_mfma_f32_16x16x32_bf16(af[i], bf[j], acc[i][j], 0, 0, 0);
    }
  };

  GSTAGE(As[0], Bs[0], 0);
  for (int kt = 0; kt < 16; ++kt) {
    BARRIER();
    SCHEDB();
    if (kt < 15) {
      GSTAGE(As[(kt + 1) & 1], Bs[(kt + 1) & 1], (kt + 1) * 64);
      asm volatile("s_waitcnt vmcnt(8)" ::: "memory");
    } else {
      asm volatile("s_waitcnt vmcnt(0)" ::: "memory");
    }
    SCHEDB();
    BARRIER();
    SCHEDB();
    GCOMP(As[kt & 1], Bs[kt & 1]);
  }

  float bcol[4];
#pragma unroll
  for (int j = 0; j < 4; ++j) bcol[j] = bias[bn + wn * 64 + j * 16 + lr];
#pragma unroll
  for (int i = 0; i < 4; ++i) {
    long m0 = bm + wm * 64 + i * 16 + lg * 4;
#pragma unroll
    for (int j = 0; j < 4; ++j) {
      long n = bn + wn * 64 + j * 16 + lr;
#pragma unroll
      for (int r = 0; r < 4; ++r)
        C[(m0 + r) * Nd + n] = acc[i][j][r] + bcol[j];
    }
  }
}

// ---------- flash attention: R6 per-wave structure, 2-wave blocks for de-phasing ----------
// Same 64 q-rows/wave, same ATILE/EXPPACK/SGB; block = 2 waves (128 thr), grid 1024,
// 2 LDS buffers (32KB) depth-1 prefetch (K/V L2-resident; stage covered by ATILE).
// 4 independent barrier groups/CU instead of 2 -> lockstep-quorum/de-phasing test.
__global__ __launch_bounds__(128, 2) void k_attn(const u16* __restrict__ q, const u16* __restrict__ k,
                                                 const u16* __restrict__ vT, u16* __restrict__ o) {
  __shared__ alignas(16) u16 Ks[2][64 * 64];
  __shared__ alignas(16) u16 Vs[2][64 * 64];
  const int t = threadIdx.x;
  const int lane = t & 63;
  const int wv = t >> 6;                 // 0..1
  const int l5 = lane & 31, hi = lane >> 5;
  const int r8 = lane >> 3, c8 = lane & 7;
  const int rx = l5 & 7;

  // XCD-aware block swizzle (1024 % 8 == 0, bijective); 16 consecutive ob = one (b,h)
  const int wg = blockIdx.x;                      // 0..1023
  const int ob = (wg & 7) * 128 + (wg >> 3);
  const int qt = ob & 15, h = (ob >> 4) & 15, b = ob >> 8;

  const int qrow0 = qt * 128 + wv * 64 + l5;      // q-block A
  const u16* qpA = q + ((long)(b * 2048 + qrow0) * 1024 + h * 64);
  const u16* qpB = qpA + 32 * 1024;               // q-block B (+32 rows)
  s8v qfA[4], qfB[4];
#pragma unroll
  for (int s = 0; s < 4; ++s) {
    qfA[s] = *(const s8v*)(qpA + s * 16 + hi * 8);
    qfB[s] = *(const s8v*)(qpB + s * 16 + hi * 8);
  }

  // pre-swizzled global sources (linear LDS dest; row&7 == r8)
  const u16* Kpp = k + (long)b * 2048 * 1024 + h * 64 + (long)r8 * 1024 + ((c8 ^ r8) * 8);
  const u16* Vpp = vT + (long)(b * 16 + h) * 131072 + (long)r8 * 2048 + ((c8 ^ r8) * 8);

  f32x16 accA0 = {}, accA1 = {}, accB0 = {}, accB1 = {};
  float lA = 0.f, lB = 0.f;

  int offs[4];
#pragma unroll
  for (int s = 0; s < 4; ++s) offs[s] = ((2 * s + hi) ^ rx) * 8;
  const int rb0 = l5 * 64, rb1 = rb0 + 2048;

  auto ASTAGE = [&](int buf, int kv) {            // wave wv stages rows [wv*32, wv*32+32)
#pragma unroll
    for (int r0 = 0; r0 < 4; ++r0) {
      int rowo = wv * 32 + r0 * 8;
      gl16(Kpp + ((long)kv + rowo) * 1024, &Ks[buf][rowo * 64]);
      gl16(Vpp + (long)rowo * 2048 + kv,   &Vs[buf][rowo * 64]);
    }
  };

  auto EXPPACK = [&](const f32x16& sv, PU& u0, PU& u1, float& l) {
#pragma unroll
    for (int r1 = 0; r1 < 4; ++r1) {
      float p0 = __builtin_amdgcn_exp2f(sv[4 * r1 + 0]);
      float p1 = __builtin_amdgcn_exp2f(sv[4 * r1 + 1]);
      float p2 = __builtin_amdgcn_exp2f(sv[4 * r1 + 2]);
      float p3 = __builtin_amdgcn_exp2f(sv[4 * r1 + 3]);
      l += (p0 + p1) + (p2 + p3);
      if (r1 < 2) {
        u0.w[(r1 & 1) * 2 + 0] = pk2(p0, p1);
        u0.w[(r1 & 1) * 2 + 1] = pk2(p2, p3);
      } else {
        u1.w[(r1 & 1) * 2 + 0] = pk2(p0, p1);
        u1.w[(r1 & 1) * 2 + 1] = pk2(p2, p3);
      }
    }
  };

  auto ATILE = [&](int buf) {
    const u16* Ksb = Ks[buf];
    const u16* Vsb = Vs[buf];
    PU paU[4], pbU[4];
    f32x16 sA0 = {}, sB0 = {}, sA1 = {}, sB1 = {};
    s8v kf0[4], kf1[4];
    // ---- P1: kf reads + QK kb0 ----
#pragma unroll
    for (int s = 0; s < 4; ++s) {
      kf0[s] = *(const s8v*)(Ksb + rb0 + offs[s]);
      kf1[s] = *(const s8v*)(Ksb + rb1 + offs[s]);
    }
#pragma unroll
    for (int s = 0; s < 4; ++s) {
      sA0 = __builtin_amdgcn_mfma_f32_32x32x16_bf16(kf0[s], qfA[s], sA0, 0, 0, 0);
      sB0 = __builtin_amdgcn_mfma_f32_32x32x16_bf16(kf0[s], qfB[s], sB0, 0, 0, 0);
    }
#pragma unroll
    for (int g = 0; g < 4; ++g) { SGB(0x100, 2); SGB(0x8, 2); }
    SCHEDB();
    // ---- P2: QK kb1 interleaved with exp/pack kb0 ----
#pragma unroll
    for (int s = 0; s < 4; ++s) {
      sA1 = __builtin_amdgcn_mfma_f32_32x32x16_bf16(kf1[s], qfA[s], sA1, 0, 0, 0);
      sB1 = __builtin_amdgcn_mfma_f32_32x32x16_bf16(kf1[s], qfB[s], sB1, 0, 0, 0);
    }
    EXPPACK(sA0, paU[0], paU[1], lA);
    EXPPACK(sB0, pbU[0], pbU[1], lB);
#pragma unroll
    for (int g = 0; g < 8; ++g) { SGB(0x8, 1); SGB(0x2, 9); }
    SCHEDB();
    // ---- P3: vf reads + PV (kb0 packs) interleaved with exp/pack kb1 ----
    s8v vf0[4], vf1[4];
#pragma unroll
    for (int s = 0; s < 4; ++s) {
      vf0[s] = *(const s8v*)(Vsb + rb0 + offs[s]);
      vf1[s] = *(const s8v*)(Vsb + rb1 + offs[s]);
    }
#pragma unroll
    for (int s2 = 0; s2 < 2; ++s2) {
      accA0 = __builtin_amdgcn_mfma_f32_32x32x16_bf16(vf0[s2], paU[s2].v, accA0, 0, 0, 0);
      accA1 = __builtin_amdgcn_mfma_f32_32x32x16_bf16(vf1[s2], paU[s2].v, accA1, 0, 0, 0);
      accB0 = __builtin_amdgcn_mfma_f32_32x32x16_bf16(vf0[s2], pbU[s2].v, accB0, 0, 0, 0);
      accB1 = __builtin_amdgcn_mfma_f32_32x32x16_bf16(vf1[s2], pbU[s2].v, accB1, 0, 0, 0);
    }
    EXPPACK(sA1, paU[2], paU[3], lA);
    EXPPACK(sB1, pbU[2], pbU[3], lB);
#pragma unroll
    for (int g = 0; g < 8; ++g) { SGB(0x100, 1); SGB(0x8, 1); SGB(0x2, 9); }
    SCHEDB();
    // ---- P4: PV (kb1 packs) ----
#pragma unroll
    for (int s2 = 2; s2 < 4; ++s2) {
      accA0 = __builtin_amdgcn_mfma_f32_32x32x16_bf16(vf0[s2], paU[s2].v, accA0, 0, 0, 0);
      accA1 = __builtin_amdgcn_mfma_f32_32x32x16_bf16(vf1[s2], paU[s2].v, accA1, 0, 0, 0);
      accB0 = __builtin_amdgcn_mfma_f32_32x32x16_bf16(vf0[s2], pbU[s2].v, accB0, 0, 0, 0);
      accB1 = __builtin_amdgcn_mfma_f32_32x32x16_bf16(vf1[s2], pbU[s2].v, accB1, 0, 0, 0);
    }
  };

  // ---- pipelined loop: 32 tiles, 2 buffers, depth-1 (stage covered by ATILE) ----
  ASTAGE(0, 0);
  asm volatile("s_waitcnt vmcnt(0)" ::: "memory");
  SCHEDB();
  BARRIER();
  SCHEDB();
  for (int tt = 0; tt < 31; ++tt) {
    ASTAGE((tt + 1) & 1, (tt + 1) * 64);   // issue next tile's 8 gl16
    ATILE(tt & 1);                          // compute current (covers stage latency)
    asm volatile("s_waitcnt vmcnt(0) lgkmcnt(0)" ::: "memory");
    SCHEDB();
    BARRIER();                              // next tile staged everywhere; readers drained
    SCHEDB();
  }
  ATILE(31 & 1);

  lA += __shfl_xor(lA, 32);
  lB += __shfl_xor(lB, 32);
  float iA = 1.0f / lA, iB = 1.0f / lB;
  u16* opA = o + ((long)(b * 2048 + qrow0) * 1024 + h * 64);
  u16* opB = opA + 32 * 1024;
#pragma unroll
  for (int kb = 0; kb < 2; ++kb) {
#pragma unroll
    for (int r1 = 0; r1 < 4; ++r1) {
      u32x2 ca, cb;
      float a0 = kb ? accA1[4 * r1 + 0] : accA0[4 * r1 + 0];
      float a1 = kb ? accA1[4 * r1 + 1] : accA0[4 * r1 + 1];
      float a2 = kb ? accA1[4 * r1 + 2] : accA0[4 * r1 + 2];
      float a3 = kb ? accA1[4 * r1 + 3] : accA0[4 * r1 + 3];
      ca[0] = pk2(a0 * iA, a1 * iA);
      ca[1] = pk2(a2 * iA, a3 * iA);
      *(u32x2*)(opA + kb * 32 + r1 * 8 + hi * 4) = ca;
      float b0v = kb ? accB1[4 * r1 + 0] : accB0[4 * r1 + 0];
      float b1v = kb ? accB1[4 * r1 + 1] : accB0[4 * r1 + 1];
      float b2v = kb ? accB1[4 * r1 + 2] : accB0[4 * r1 + 2];
      float b3v = kb ? accB1[4 * r1 + 3] : accB0[4 * r1 + 3];
      cb[0] = pk2(b0v * iB, b1v * iB);
      cb[1] = pk2(b2v * iB, b3v * iB);
      *(u32x2*)(opB + kb * 32 + r1 * 8 + hi * 4) = cb;
    }
  }
}

extern "C" void kernel_launch(void* const* d_in, const int* in_sizes, int n_in,
                              void* d_out, int out_size, void* d_ws, size_t ws_size,
                              hipStream_t stream) {
  const float* Q  = (const float*)d_in[0];
  const float* K  = (const float*)d_in[1];
  const float* V  = (const float*)d_in[2];
  const float* Wq = (const float*)d_in[3];
  const float* bq = (const float*)d_in[4];
  const float* Wk = (const float*)d_in[5];
  const float* bk = (const float*)d_in[6];
  const float* Wv = (const float*)d_in[7];
  const float* bvp = (const float*)d_in[8];
  const float* Wo = (const float*)d_in[9];
  const float* bo = (const float*)d_in[10];
  float* out = (float*)d_out;

  char* ws = (char*)d_ws;
  const size_t MB16 = (size_t)8192 * 1024 * 2;   // 16 MiB (one 8192x1024 bf16)
  u16* WqT = (u16*)(ws);
  u16* WkT = (u16*)(ws + ((size_t)2 << 20));
  u16* WvT = (u16*)(ws + ((size_t)4 << 20));
  u16* WoT = (u16*)(ws + ((size_t)6 << 20));
  u16* qws = (u16*)(ws + ((size_t)8 << 20));
  u16* kws = (u16*)(ws + ((size_t)8 << 20) + MB16);
  u16* vTs = (u16*)(ws + ((size_t)8 << 20) + 2 * MB16);
  u16* ows = (u16*)(ws + ((size_t)8 << 20) + 3 * MB16);

  k_convW_all<<<dim3(16, 16, 4), 256, 0, stream>>>(Wq, Wk, Wv, Wo, WqT, WkT, WvT, WoT);

  k_gemm3f<<<dim3(64, 8, 3), 256, 0, stream>>>(Q, K, V, WqT, WkT, WvT,
                                               bq, bk, bvp, qws, kws, vTs);

  k_attn<<<dim3(1024), 128, 0, stream>>>(qws, kws, vTs, ows);

  k_gemmo<<<dim3(64, 8), 256, 0, stream>>>(ows, WoT, bo, out);
}

// Round 19
// 184.328 us; speedup vs baseline: 1.0238x; 1.0238x over previous
//
#include <hip/hip_runtime.h>
#include <hip/hip_bf16.h>
#include <stdint.h>

typedef unsigned short u16;
typedef uint32_t u32;
typedef __attribute__((ext_vector_type(4))) float f32x4;
typedef __attribute__((ext_vector_type(16))) float f32x16;
typedef __attribute__((ext_vector_type(8))) short s8v;     // 8 bf16 as shorts (4 VGPR)
typedef __attribute__((ext_vector_type(4))) unsigned short u16x4;
typedef __attribute__((ext_vector_type(2))) uint32_t u32x2;
typedef __attribute__((ext_vector_type(4))) uint32_t u32x4;

#define SCALE_Q 0.18033688f   // (1/8) * log2(e): scores come out in log2 domain

union PU { s8v v; u32 w[4]; };

__device__ __forceinline__ u16 f2bf(float f) {
  union { float f; uint32_t u; } v; v.f = f;
  uint32_t r = v.u + 0x7fffu + ((v.u >> 16) & 1u);   // RNE, no NaN inputs
  return (u16)(r >> 16);
}

__device__ __forceinline__ u32 pk2(float lo, float hi) {
  __hip_bfloat162 h = __float22bfloat162_rn(float2{lo, hi});
  union { __hip_bfloat162 h; u32 u; } c; c.h = h; return c.u;
}

// async global->LDS, 16B per lane; LDS base is WAVE-UNIFORM (HW adds lane*16)
__device__ __forceinline__ void gl16(const void* g, void* l) {
  __builtin_amdgcn_global_load_lds((const __attribute__((address_space(1))) u32*)g,
                                   (__attribute__((address_space(3))) u32*)l, 16, 0, 0);
}

#define BARRIER()  __builtin_amdgcn_s_barrier()
#define SCHEDB()   __builtin_amdgcn_sched_barrier(0)
#define SGB(m, n)  __builtin_amdgcn_sched_group_barrier((m), (n), 0)
#define MEMPIN()   asm volatile("" ::: "memory")   // pin VMEM issue order (counted-vmcnt rule)

// Merged weight transposes (one launch):
//  z=0..2: W[h][d][kk] f32 -> WT[n=h*64+kk][d] bf16 (q-slice folds SCALE_Q)
//  z=3   : Wo[k][n]   f32 -> WoT[n][k] bf16
__global__ __launch_bounds__(256) void k_convW_all(const float* __restrict__ wq, const float* __restrict__ wk,
                                                   const float* __restrict__ wv, const float* __restrict__ wo,
                                                   u16* __restrict__ oq, u16* __restrict__ ok,
                                                   u16* __restrict__ ov, u16* __restrict__ oo) {
  __shared__ float T[64][65];
  const int z = blockIdx.z;
  const int t = threadIdx.x;
  if (z < 3) {
    const int h = blockIdx.y, d0 = blockIdx.x * 64;
    const float* w = z == 0 ? wq : (z == 1 ? wk : wv);
    u16* o = z == 0 ? oq : (z == 1 ? ok : ov);
    const float scale = z == 0 ? SCALE_Q : 1.0f;
#pragma unroll
    for (int i = 0; i < 16; ++i) {
      int f = t + i * 256;
      T[f >> 6][f & 63] = w[(h * 1024 + d0 + (f >> 6)) * 64 + (f & 63)];
    }
    __syncthreads();
#pragma unroll
    for (int i = 0; i < 16; ++i) {
      int g = t + i * 256;
      o[(h * 64 + (g >> 6)) * 1024 + d0 + (g & 63)] = f2bf(T[g & 63][g >> 6] * scale);
    }
  } else {
    const int n0 = blockIdx.x * 64, c0 = blockIdx.y * 64;
#pragma unroll
    for (int i = 0; i < 16; ++i) {
      int f = t + i * 256;
      T[f >> 6][f & 63] = wo[(c0 + (f >> 6)) * 1024 + n0 + (f & 63)];
    }
    __syncthreads();
#pragma unroll
    for (int i = 0; i < 16; ++i) {
      int g = t + i * 256;
      oo[(n0 + (g >> 6)) * 1024 + c0 + (g & 63)] = f2bf(T[g & 63][g >> 6]);
    }
  }
}

// ---------- fused conv+QKV projection GEMM: A is f32, converted during reg-staging ----------
// Counted-vmcnt rule: BSTG's 4 gl16 and ALOAD's 8 global loads are fenced with MEMPIN()
// so issue order is guaranteed 4xgl16 then 8xload -> vmcnt(8) retires exactly the gl16s.
__global__ __launch_bounds__(256) void k_gemm3f(
    const float* __restrict__ Aq, const float* __restrict__ Ak, const float* __restrict__ Av,
    const u16* __restrict__ Bq, const u16* __restrict__ Bk, const u16* __restrict__ Bv,
    const float* __restrict__ bqp, const float* __restrict__ bkp, const float* __restrict__ bvp,
    u16* __restrict__ oq, u16* __restrict__ ok, u16* __restrict__ ov) {
  constexpr int Kd = 1024, Nd = 1024;
  __shared__ alignas(16) u16 As[128 * 64];
  __shared__ alignas(16) u16 Bs[128 * 64];
  const int z = blockIdx.z;
  const float* A = z == 0 ? Aq : (z == 1 ? Ak : Av);
  const u16* Bt = z == 0 ? Bq : (z == 1 ? Bk : Bv);
  const float* bias = z == 0 ? bqp : (z == 1 ? bkp : bvp);

  const int t = threadIdx.x;
  const int lane = t & 63;
  const int w = t >> 6;
  const int wm = w >> 1, wn = w & 1;
  const int lr = lane & 15, lg = lane >> 4;
  const long bm = blockIdx.x * 128, bn = blockIdx.y * 128;
  const int r8 = lane >> 3, c8 = lane & 7;
  const int chunk = c8 ^ r8;               // B pre-swizzled source chunk

  // A reg-stage: thread t owns rows {arow_s + 32j, j=0..3}, chunk achk (8 f32 wide)
  const int arow_s = t >> 3, achk = t & 7;
  const int aswz = (achk ^ (arow_s & 7)) * 8;      // row&7 == arow_s&7 for all j
  const float* Apf = A + (bm + arow_s) * (long)Kd + achk * 8;
  const u16* Bp = Bt + (bn + w * 8 + r8) * (long)Kd + chunk * 8;

  f32x4 acc[4][4] = {};
  float4 fa[4][2];

  auto ALOAD = [&](int kt) {
#pragma unroll
    for (int j = 0; j < 4; ++j) {
      fa[j][0] = *(const float4*)(Apf + (long)j * 32 * Kd + kt);
      fa[j][1] = *(const float4*)(Apf + (long)j * 32 * Kd + kt + 4);
    }
  };
  auto AWRITE = [&]() {
#pragma unroll
    for (int j = 0; j < 4; ++j) {
      u32x4 pk;
      pk[0] = pk2(fa[j][0].x, fa[j][0].y);
      pk[1] = pk2(fa[j][0].z, fa[j][0].w);
      pk[2] = pk2(fa[j][1].x, fa[j][1].y);
      pk[3] = pk2(fa[j][1].z, fa[j][1].w);
      *(u32x4*)(&As[(j * 32 + arow_s) * 64 + aswz]) = pk;
    }
  };
  auto BSTG = [&](int kt) {
#pragma unroll
    for (int p = 0; p < 4; ++p)
      gl16(Bp + (long)p * 32 * Kd + kt, Bs + (p * 32 + w * 8) * 64);
  };
  auto GCOMP = [&]() {
#pragma unroll
    for (int ks = 0; ks < 2; ++ks) {
      s8v af[4], bf[4];
#pragma unroll
      for (int i = 0; i < 4; ++i) {
        int arow = wm * 64 + i * 16 + lr;
        af[i] = *(const s8v*)(&As[arow * 64 + (((ks * 4 + lg) ^ (arow & 7)) * 8)]);
        int brow = wn * 64 + i * 16 + lr;
        bf[i] = *(const s8v*)(&Bs[brow * 64 + (((ks * 4 + lg) ^ (brow & 7)) * 8)]);
      }
#pragma unroll
      for (int i = 0; i < 4; ++i)
#pragma unroll
        for (int j = 0; j < 4; ++j)
          acc[i][j] = __builtin_amdgcn_mfma_f32_16x16x32_bf16(af[i], bf[j], acc[i][j], 0, 0, 0);
    }
  };

  ALOAD(0);
  for (int kt = 0; kt < 16; ++kt) {
    BARRIER();                             // all waves done reading As/Bs (prev compute)
    SCHEDB();
    AWRITE();                              // consumes fa (compiler waits on A-loads here)
    MEMPIN();
    BSTG(kt * 64);                         // 4x gl16 issued...
    MEMPIN();                              // ...strictly BEFORE the 8 A-loads below
    if (kt < 15) {
      ALOAD((kt + 1) * 64);                // in flight across next compute
      MEMPIN();
      asm volatile("s_waitcnt vmcnt(8) lgkmcnt(0)" ::: "memory");  // retires exactly the 4 gl16 + ds_writes
    } else {
      asm volatile("s_waitcnt vmcnt(0) lgkmcnt(0)" ::: "memory");
    }
    SCHEDB();
    BARRIER();                             // tile staged everywhere
    SCHEDB();
    GCOMP();
  }

  const float bscale = z == 0 ? SCALE_Q : 1.0f;
  float bcol[4];
#pragma unroll
  for (int j = 0; j < 4; ++j) bcol[j] = bias[bn + wn * 64 + j * 16 + lr] * bscale;

  if (z < 2) {
    u16* C = z == 0 ? oq : ok;
#pragma unroll
    for (int i = 0; i < 4; ++i) {
      long m0 = bm + wm * 64 + i * 16 + lg * 4;
#pragma unroll
      for (int j = 0; j < 4; ++j) {
        long n = bn + wn * 64 + j * 16 + lr;
#pragma unroll
        for (int r = 0; r < 4; ++r)
          C[(m0 + r) * Nd + n] = f2bf(acc[i][j][r] + bcol[j]);
      }
    }
  } else {
    // V out, transposed vT[((b*16+h)*64+dv)][2048] with kv-axis pi-permutation
    // (bits 3<->2 of the within-16 s offset) so PV's B-frag is lane-local in k_attn.
    u16* C = ov;
    int lgp = ((lg & 1) << 1) | (lg >> 1);
#pragma unroll
    for (int i = 0; i < 4; ++i) {
      long m0 = bm + wm * 64 + i * 16 + lgp * 4;
      int b = (int)(m0 >> 11), s0 = (int)(m0 & 2047);
#pragma unroll
      for (int j = 0; j < 4; ++j) {
        int n = (int)(bn + wn * 64 + j * 16 + lr);
        int h = n >> 6, dv = n & 63;
        u32x2 cc;
        cc[0] = pk2(acc[i][j][0] + bcol[j], acc[i][j][1] + bcol[j]);
        cc[1] = pk2(acc[i][j][2] + bcol[j], acc[i][j][3] + bcol[j]);
        *(u32x2*)(C + (long)((b * 16 + h) * 64 + dv) * 2048 + s0) = cc;
      }
    }
  }
}

// ---------- output projection GEMM (bf16 in, f32 out), counted-vmcnt pipeline ----------
__global__ __launch_bounds__(256) void k_gemmo(const u16* __restrict__ A, const u16* __restrict__ Bt,
                                               const float* __restrict__ bias, float* __restrict__ C) {
  constexpr int Kd = 1024, Nd = 1024;
  __shared__ alignas(16) u16 As[2][128 * 64];
  __shared__ alignas(16) u16 Bs[2][128 * 64];
  const int t = threadIdx.x;
  const int lane = t & 63;
  const int w = t >> 6;
  const int wm = w >> 1, wn = w & 1;
  const int lr = lane & 15, lg = lane >> 4;
  const long bm = blockIdx.x * 128, bn = blockIdx.y * 128;
  const int r8 = lane >> 3, c8 = lane & 7;
  const int chunk = c8 ^ r8;

  f32x4 acc[4][4] = {};
  const u16* Ap = A + (bm + w * 8 + r8) * (long)Kd + chunk * 8;
  const u16* Bp = Bt + (bn + w * 8 + r8) * (long)Kd + chunk * 8;

  auto GSTAGE = [&](u16* Asb, u16* Bsb, int kt) {
#pragma unroll
    for (int p = 0; p < 4; ++p) {
      gl16(Ap + (long)p * 32 * Kd + kt, Asb + (p * 32 + w * 8) * 64);
      gl16(Bp + (long)p * 32 * Kd + kt, Bsb + (p * 32 + w * 8) * 64);
    }
  };
  auto GCOMP = [&](const u16* Asb, const u16* Bsb) {
#pragma unroll
    for (int ks = 0; ks < 2; ++ks) {
      s8v af[4], bf[4];
#pragma unroll
      for (int i = 0; i < 4; ++i) {
        int arow = wm * 64 + i * 16 + lr;
        af[i] = *(const s8v*)(Asb + arow * 64 + (((ks * 4 + lg) ^ (arow & 7)) * 8));
        int brow = wn * 64 + i * 16 + lr;
        bf[i] = *(const s8v*)(Bsb + brow * 64 + (((ks * 4 + lg) ^ (brow & 7)) * 8));
      }
#pragma unroll
      for (int i = 0; i < 4; ++i)
#pragma unroll
        for (int j = 0; j < 4; ++j)
          acc[i][j] = __builtin_amdgcn_mfma_f32_16x16x32_bf16(af[i], bf[j], acc[i][j], 0, 0, 0);
    }
  };

  GSTAGE(As[0], Bs[0], 0);
  for (int kt = 0; kt < 16; ++kt) {
    BARRIER();
    SCHEDB();
    if (kt < 15) {
      GSTAGE(As[(kt + 1) & 1], Bs[(kt + 1) & 1], (kt + 1) * 64);
      asm volatile("s_waitcnt vmcnt(8)" ::: "memory");
    } else {
      asm volatile("s_waitcnt vmcnt(0)" ::: "memory");
    }
    SCHEDB();
    BARRIER();
    SCHEDB();
    GCOMP(As[kt & 1], Bs[kt & 1]);
  }

  float bcol[4];
#pragma unroll
  for (int j = 0; j < 4; ++j) bcol[j] = bias[bn + wn * 64 + j * 16 + lr];
#pragma unroll
  for (int i = 0; i < 4; ++i) {
    long m0 = bm + wm * 64 + i * 16 + lg * 4;
#pragma unroll
    for (int j = 0; j < 4; ++j) {
      long n = bn + wn * 64 + j * 16 + lr;
#pragma unroll
      for (int r = 0; r < 4; ++r)
        C[(m0 + r) * Nd + n] = acc[i][j][r] + bcol[j];
    }
  }
}

// ---------- flash attention: R6 version (best measured, 91us) ----------
// 4 waves x 64 q, kb-split pipeline + sched_group_barrier; KVBLK=64; P in registers.
__global__ __launch_bounds__(256, 2) void k_attn(const u16* __restrict__ q, const u16* __restrict__ k,
                                                 const u16* __restrict__ vT, u16* __restrict__ o) {
  __shared__ alignas(16) u16 Ks[4][64 * 64];
  __shared__ alignas(16) u16 Vs[4][64 * 64];
  const int t = threadIdx.x;
  const int lane = t & 63;
  const int wv = t >> 6;                 // 0..3
  const int l5 = lane & 31, hi = lane >> 5;
  const int r8 = lane >> 3, c8 = lane & 7;
  const int rx = l5 & 7;

  // XCD-aware block swizzle: 8 qt-blocks of one (b,h) land on one XCD
  const int wg = blockIdx.x;                      // 0..511
  const int ob = (wg & 7) * 64 + (wg >> 3);       // bijective
  const int qt = ob & 7, h = (ob >> 3) & 15, b = ob >> 7;

  const int qrow0 = qt * 256 + wv * 64 + l5;      // q-block A
  const u16* qpA = q + ((long)(b * 2048 + qrow0) * 1024 + h * 64);
  const u16* qpB = qpA + 32 * 1024;               // q-block B (+32 rows)
  s8v qfA[4], qfB[4];
#pragma unroll
  for (int s = 0; s < 4; ++s) {
    qfA[s] = *(const s8v*)(qpA + s * 16 + hi * 8);
    qfB[s] = *(const s8v*)(qpB + s * 16 + hi * 8);
  }

  // pre-swizzled global sources (linear LDS dest; row&7 == r8)
  const u16* Kpp = k + (long)b * 2048 * 1024 + h * 64 + (long)r8 * 1024 + ((c8 ^ r8) * 8);
  const u16* Vpp = vT + (long)(b * 16 + h) * 131072 + (long)r8 * 2048 + ((c8 ^ r8) * 8);

  f32x16 accA0 = {}, accA1 = {}, accB0 = {}, accB1 = {};
  float lA = 0.f, lB = 0.f;

  int offs[4];
#pragma unroll
  for (int s = 0; s < 4; ++s) offs[s] = ((2 * s + hi) ^ rx) * 8;
  const int rb0 = l5 * 64, rb1 = rb0 + 2048;

  auto ASTAGE = [&](int buf, int kv) {            // wave wv stages rows [wv*16, wv*16+16)
#pragma unroll
    for (int r0 = 0; r0 < 2; ++r0) {
      int rowo = wv * 16 + r0 * 8;
      gl16(Kpp + ((long)kv + rowo) * 1024, &Ks[buf][rowo * 64]);
      gl16(Vpp + (long)rowo * 2048 + kv,   &Vs[buf][rowo * 64]);
    }
  };

  auto EXPPACK = [&](const f32x16& sv, PU& u0, PU& u1, float& l) {
#pragma unroll
    for (int r1 = 0; r1 < 4; ++r1) {
      float p0 = __builtin_amdgcn_exp2f(sv[4 * r1 + 0]);
      float p1 = __builtin_amdgcn_exp2f(sv[4 * r1 + 1]);
      float p2 = __builtin_amdgcn_exp2f(sv[4 * r1 + 2]);
      float p3 = __builtin_amdgcn_exp2f(sv[4 * r1 + 3]);
      l += (p0 + p1) + (p2 + p3);
      if (r1 < 2) {
        u0.w[(r1 & 1) * 2 + 0] = pk2(p0, p1);
        u0.w[(r1 & 1) * 2 + 1] = pk2(p2, p3);
      } else {
        u1.w[(r1 & 1) * 2 + 0] = pk2(p0, p1);
        u1.w[(r1 & 1) * 2 + 1] = pk2(p2, p3);
      }
    }
  };

  auto ATILE = [&](int buf) {
    const u16* Ksb = Ks[buf];
    const u16* Vsb = Vs[buf];
    PU paU[4], pbU[4];
    f32x16 sA0 = {}, sB0 = {}, sA1 = {}, sB1 = {};
    s8v kf0[4], kf1[4];
    // ---- P1: kf reads + QK kb0 ----
#pragma unroll
    for (int s = 0; s < 4; ++s) {
      kf0[s] = *(const s8v*)(Ksb + rb0 + offs[s]);
      kf1[s] = *(const s8v*)(Ksb + rb1 + offs[s]);
    }
#pragma unroll
    for (int s = 0; s < 4; ++s) {
      sA0 = __builtin_amdgcn_mfma_f32_32x32x16_bf16(kf0[s], qfA[s], sA0, 0, 0, 0);
      sB0 = __builtin_amdgcn_mfma_f32_32x32x16_bf16(kf0[s], qfB[s], sB0, 0, 0, 0);
    }
#pragma unroll
    for (int g = 0; g < 4; ++g) { SGB(0x100, 2); SGB(0x8, 2); }
    SCHEDB();
    // ---- P2: QK kb1 interleaved with exp/pack kb0 ----
#pragma unroll
    for (int s = 0; s < 4; ++s) {
      sA1 = __builtin_amdgcn_mfma_f32_32x32x16_bf16(kf1[s], qfA[s], sA1, 0, 0, 0);
      sB1 = __builtin_amdgcn_mfma_f32_32x32x16_bf16(kf1[s], qfB[s], sB1, 0, 0, 0);
    }
    EXPPACK(sA0, paU[0], paU[1], lA);
    EXPPACK(sB0, pbU[0], pbU[1], lB);
#pragma unroll
    for (int g = 0; g < 8; ++g) { SGB(0x8, 1); SGB(0x2, 9); }
    SCHEDB();
    // ---- P3: vf reads + PV (kb0 packs) interleaved with exp/pack kb1 ----
    s8v vf0[4], vf1[4];
#pragma unroll
    for (int s = 0; s < 4; ++s) {
      vf0[s] = *(const s8v*)(Vsb + rb0 + offs[s]);
      vf1[s] = *(const s8v*)(Vsb + rb1 + offs[s]);
    }
#pragma unroll
    for (int s2 = 0; s2 < 2; ++s2) {
      accA0 = __builtin_amdgcn_mfma_f32_32x32x16_bf16(vf0[s2], paU[s2].v, accA0, 0, 0, 0);
      accA1 = __builtin_amdgcn_mfma_f32_32x32x16_bf16(vf1[s2], paU[s2].v, accA1, 0, 0, 0);
      accB0 = __builtin_amdgcn_mfma_f32_32x32x16_bf16(vf0[s2], pbU[s2].v, accB0, 0, 0, 0);
      accB1 = __builtin_amdgcn_mfma_f32_32x32x16_bf16(vf1[s2], pbU[s2].v, accB1, 0, 0, 0);
    }
    EXPPACK(sA1, paU[2], paU[3], lA);
    EXPPACK(sB1, pbU[2], pbU[3], lB);
#pragma unroll
    for (int g = 0; g < 8; ++g) { SGB(0x100, 1); SGB(0x8, 1); SGB(0x2, 9); }
    SCHEDB();
    // ---- P4: PV (kb1 packs) ----
#pragma unroll
    for (int s2 = 2; s2 < 4; ++s2) {
      accA0 = __builtin_amdgcn_mfma_f32_32x32x16_bf16(vf0[s2], paU[s2].v, accA0, 0, 0, 0);
      accA1 = __builtin_amdgcn_mfma_f32_32x32x16_bf16(vf1[s2], paU[s2].v, accA1, 0, 0, 0);
      accB0 = __builtin_amdgcn_mfma_f32_32x32x16_bf16(vf0[s2], pbU[s2].v, accB0, 0, 0, 0);
      accB1 = __builtin_amdgcn_mfma_f32_32x32x16_bf16(vf1[s2], pbU[s2].v, accB1, 0, 0, 0);
    }
  };

  // ---- pipelined loop: 32 tiles, 4 buffers, prefetch depth 2 ----
  ASTAGE(0, 0);
  ASTAGE(1, 64);
  asm volatile("s_waitcnt vmcnt(4)" ::: "memory");
  SCHEDB();
  BARRIER();
  SCHEDB();
  for (int tt = 0; tt < 30; ++tt) {
    ASTAGE((tt + 2) & 3, (tt + 2) * 64);
    ATILE(tt & 3);
    asm volatile("s_waitcnt vmcnt(4) lgkmcnt(0)" ::: "memory");
    SCHEDB();
    BARRIER();
    SCHEDB();
  }
  ATILE(30 & 3);
  asm volatile("s_waitcnt vmcnt(0) lgkmcnt(0)" ::: "memory");
  SCHEDB();
  BARRIER();
  SCHEDB();
  ATILE(31 & 3);

  lA += __shfl_xor(lA, 32);
  lB += __shfl_xor(lB, 32);
  float iA = 1.0f / lA, iB = 1.0f / lB;
  u16* opA = o + ((long)(b * 2048 + qrow0) * 1024 + h * 64);
  u16* opB = opA + 32 * 1024;
#pragma unroll
  for (int kb = 0; kb < 2; ++kb) {
#pragma unroll
    for (int r1 = 0; r1 < 4; ++r1) {
      u32x2 ca, cb;
      float a0 = kb ? accA1[4 * r1 + 0] : accA0[4 * r1 + 0];
      float a1 = kb ? accA1[4 * r1 + 1] : accA0[4 * r1 + 1];
      float a2 = kb ? accA1[4 * r1 + 2] : accA0[4 * r1 + 2];
      float a3 = kb ? accA1[4 * r1 + 3] : accA0[4 * r1 + 3];
      ca[0] = pk2(a0 * iA, a1 * iA);
      ca[1] = pk2(a2 * iA, a3 * iA);
      *(u32x2*)(opA + kb * 32 + r1 * 8 + hi * 4) = ca;
      float b0v = kb ? accB1[4 * r1 + 0] : accB0[4 * r1 + 0];
      float b1v = kb ? accB1[4 * r1 + 1] : accB0[4 * r1 + 1];
      float b2v = kb ? accB1[4 * r1 + 2] : accB0[4 * r1 + 2];
      float b3v = kb ? accB1[4 * r1 + 3] : accB0[4 * r1 + 3];
      cb[0] = pk2(b0v * iB, b1v * iB);
      cb[1] = pk2(b2v * iB, b3v * iB);
      *(u32x2*)(opB + kb * 32 + r1 * 8 + hi * 4) = cb;
    }
  }
}

extern "C" void kernel_launch(void* const* d_in, const int* in_sizes, int n_in,
                              void* d_out, int out_size, void* d_ws, size_t ws_size,
                              hipStream_t stream) {
  const float* Q  = (const float*)d_in[0];
  const float* K  = (const float*)d_in[1];
  const float* V  = (const float*)d_in[2];
  const float* Wq = (const float*)d_in[3];
  const float* bq = (const float*)d_in[4];
  const float* Wk = (const float*)d_in[5];
  const float* bk = (const float*)d_in[6];
  const float* Wv = (const float*)d_in[7];
  const float* bvp = (const float*)d_in[8];
  const float* Wo = (const float*)d_in[9];
  const float* bo = (const float*)d_in[10];
  float* out = (float*)d_out;

  char* ws = (char*)d_ws;
  const size_t MB16 = (size_t)8192 * 1024 * 2;   // 16 MiB (one 8192x1024 bf16)
  u16* WqT = (u16*)(ws);
  u16* WkT = (u16*)(ws + ((size_t)2 << 20));
  u16* WvT = (u16*)(ws + ((size_t)4 << 20));
  u16* WoT = (u16*)(ws + ((size_t)6 << 20));
  u16* qws = (u16*)(ws + ((size_t)8 << 20));
  u16* kws = (u16*)(ws + ((size_t)8 << 20) + MB16);
  u16* vTs = (u16*)(ws + ((size_t)8 << 20) + 2 * MB16);
  u16* ows = (u16*)(ws + ((size_t)8 << 20) + 3 * MB16);

  k_convW_all<<<dim3(16, 16, 4), 256, 0, stream>>>(Wq, Wk, Wv, Wo, WqT, WkT, WvT, WoT);

  k_gemm3f<<<dim3(64, 8, 3), 256, 0, stream>>>(Q, K, V, WqT, WkT, WvT,
                                               bq, bk, bvp, qws, kws, vTs);

  k_attn<<<dim3(512), 256, 0, stream>>>(qws, kws, vTs, ows);

  k_gemmo<<<dim3(64, 8), 256, 0, stream>>>(ows, WoT, bo, out);
}

// Round 20
// 181.765 us; speedup vs baseline: 1.0382x; 1.0141x over previous
//
#include <hip/hip_runtime.h>
#include <hip/hip_bf16.h>
#include <stdint.h>

typedef unsigned short u16;
typedef uint32_t u32;
typedef __attribute__((ext_vector_type(4))) float f32x4;
typedef __attribute__((ext_vector_type(16))) float f32x16;
typedef __attribute__((ext_vector_type(8))) short s8v;     // 8 bf16 as shorts (4 VGPR)
typedef __attribute__((ext_vector_type(4))) unsigned short u16x4;
typedef __attribute__((ext_vector_type(2))) uint32_t u32x2;
typedef __attribute__((ext_vector_type(4))) uint32_t u32x4;

#define SCALE_Q 0.18033688f   // (1/8) * log2(e): scores come out in log2 domain

union PU { s8v v; u32 w[4]; };

__device__ __forceinline__ u16 f2bf(float f) {
  union { float f; uint32_t u; } v; v.f = f;
  uint32_t r = v.u + 0x7fffu + ((v.u >> 16) & 1u);   // RNE, no NaN inputs
  return (u16)(r >> 16);
}

__device__ __forceinline__ u32 pk2(float lo, float hi) {
  __hip_bfloat162 h = __float22bfloat162_rn(float2{lo, hi});
  union { __hip_bfloat162 h; u32 u; } c; c.h = h; return c.u;
}

// async global->LDS, 16B per lane; LDS base is WAVE-UNIFORM (HW adds lane*16)
__device__ __forceinline__ void gl16(const void* g, void* l) {
  __builtin_amdgcn_global_load_lds((const __attribute__((address_space(1))) u32*)g,
                                   (__attribute__((address_space(3))) u32*)l, 16, 0, 0);
}

#define BARRIER()  __builtin_amdgcn_s_barrier()
#define SCHEDB()   __builtin_amdgcn_sched_barrier(0)
#define SGB(m, n)  __builtin_amdgcn_sched_group_barrier((m), (n), 0)
#define MEMPIN()   asm volatile("" ::: "memory")   // pin VMEM issue order (counted-vmcnt rule)

// Merged weight transposes (one launch):
//  z=0..2: W[h][d][kk] f32 -> WT[n=h*64+kk][d] bf16 (q-slice folds SCALE_Q)
//  z=3   : Wo[k][n]   f32 -> WoT[n][k] bf16
__global__ __launch_bounds__(256) void k_convW_all(const float* __restrict__ wq, const float* __restrict__ wk,
                                                   const float* __restrict__ wv, const float* __restrict__ wo,
                                                   u16* __restrict__ oq, u16* __restrict__ ok,
                                                   u16* __restrict__ ov, u16* __restrict__ oo) {
  __shared__ float T[64][65];
  const int z = blockIdx.z;
  const int t = threadIdx.x;
  if (z < 3) {
    const int h = blockIdx.y, d0 = blockIdx.x * 64;
    const float* w = z == 0 ? wq : (z == 1 ? wk : wv);
    u16* o = z == 0 ? oq : (z == 1 ? ok : ov);
    const float scale = z == 0 ? SCALE_Q : 1.0f;
#pragma unroll
    for (int i = 0; i < 16; ++i) {
      int f = t + i * 256;
      T[f >> 6][f & 63] = w[(h * 1024 + d0 + (f >> 6)) * 64 + (f & 63)];
    }
    __syncthreads();
#pragma unroll
    for (int i = 0; i < 16; ++i) {
      int g = t + i * 256;
      o[(h * 64 + (g >> 6)) * 1024 + d0 + (g & 63)] = f2bf(T[g & 63][g >> 6] * scale);
    }
  } else {
    const int n0 = blockIdx.x * 64, c0 = blockIdx.y * 64;
#pragma unroll
    for (int i = 0; i < 16; ++i) {
      int f = t + i * 256;
      T[f >> 6][f & 63] = wo[(c0 + (f >> 6)) * 1024 + n0 + (f & 63)];
    }
    __syncthreads();
#pragma unroll
    for (int i = 0; i < 16; ++i) {
      int g = t + i * 256;
      oo[(n0 + (g >> 6)) * 1024 + c0 + (g & 63)] = f2bf(T[g & 63][g >> 6]);
    }
  }
}

// ---------- fused conv+QKV projection GEMM: A is f32, converted during reg-staging ----------
// Counted-vmcnt rule: BSTG's 4 gl16 and ALOAD's 8 global loads are fenced with MEMPIN()
// so issue order is guaranteed 4xgl16 then 8xload -> vmcnt(8) retires exactly the gl16s.
__global__ __launch_bounds__(256) void k_gemm3f(
    const float* __restrict__ Aq, const float* __restrict__ Ak, const float* __restrict__ Av,
    const u16* __restrict__ Bq, const u16* __restrict__ Bk, const u16* __restrict__ Bv,
    const float* __restrict__ bqp, const float* __restrict__ bkp, const float* __restrict__ bvp,
    u16* __restrict__ oq, u16* __restrict__ ok, u16* __restrict__ ov) {
  constexpr int Kd = 1024, Nd = 1024;
  __shared__ alignas(16) u16 As[128 * 64];
  __shared__ alignas(16) u16 Bs[128 * 64];
  const int z = blockIdx.z;
  const float* A = z == 0 ? Aq : (z == 1 ? Ak : Av);
  const u16* Bt = z == 0 ? Bq : (z == 1 ? Bk : Bv);
  const float* bias = z == 0 ? bqp : (z == 1 ? bkp : bvp);

  const int t = threadIdx.x;
  const int lane = t & 63;
  const int w = t >> 6;
  const int wm = w >> 1, wn = w & 1;
  const int lr = lane & 15, lg = lane >> 4;
  const long bm = blockIdx.x * 128, bn = blockIdx.y * 128;
  const int r8 = lane >> 3, c8 = lane & 7;
  const int chunk = c8 ^ r8;               // B pre-swizzled source chunk

  // A reg-stage: thread t owns rows {arow_s + 32j, j=0..3}, chunk achk (8 f32 wide)
  const int arow_s = t >> 3, achk = t & 7;
  const int aswz = (achk ^ (arow_s & 7)) * 8;      // row&7 == arow_s&7 for all j
  const float* Apf = A + (bm + arow_s) * (long)Kd + achk * 8;
  const u16* Bp = Bt + (bn + w * 8 + r8) * (long)Kd + chunk * 8;

  f32x4 acc[4][4] = {};
  float4 fa[4][2];

  auto ALOAD = [&](int kt) {
#pragma unroll
    for (int j = 0; j < 4; ++j) {
      fa[j][0] = *(const float4*)(Apf + (long)j * 32 * Kd + kt);
      fa[j][1] = *(const float4*)(Apf + (long)j * 32 * Kd + kt + 4);
    }
  };
  auto AWRITE = [&]() {
#pragma unroll
    for (int j = 0; j < 4; ++j) {
      u32x4 pk;
      pk[0] = pk2(fa[j][0].x, fa[j][0].y);
      pk[1] = pk2(fa[j][0].z, fa[j][0].w);
      pk[2] = pk2(fa[j][1].x, fa[j][1].y);
      pk[3] = pk2(fa[j][1].z, fa[j][1].w);
      *(u32x4*)(&As[(j * 32 + arow_s) * 64 + aswz]) = pk;
    }
  };
  auto BSTG = [&](int kt) {
#pragma unroll
    for (int p = 0; p < 4; ++p)
      gl16(Bp + (long)p * 32 * Kd + kt, Bs + (p * 32 + w * 8) * 64);
  };
  auto GCOMP = [&]() {
#pragma unroll
    for (int ks = 0; ks < 2; ++ks) {
      s8v af[4], bf[4];
#pragma unroll
      for (int i = 0; i < 4; ++i) {
        int arow = wm * 64 + i * 16 + lr;
        af[i] = *(const s8v*)(&As[arow * 64 + (((ks * 4 + lg) ^ (arow & 7)) * 8)]);
        int brow = wn * 64 + i * 16 + lr;
        bf[i] = *(const s8v*)(&Bs[brow * 64 + (((ks * 4 + lg) ^ (brow & 7)) * 8)]);
      }
#pragma unroll
      for (int i = 0; i < 4; ++i)
#pragma unroll
        for (int j = 0; j < 4; ++j)
          acc[i][j] = __builtin_amdgcn_mfma_f32_16x16x32_bf16(af[i], bf[j], acc[i][j], 0, 0, 0);
    }
  };

  ALOAD(0);
  for (int kt = 0; kt < 16; ++kt) {
    BARRIER();                             // all waves done reading As/Bs (prev compute)
    SCHEDB();
    AWRITE();                              // consumes fa (compiler waits on A-loads here)
    MEMPIN();
    BSTG(kt * 64);                         // 4x gl16 issued...
    MEMPIN();                              // ...strictly BEFORE the 8 A-loads below
    if (kt < 15) {
      ALOAD((kt + 1) * 64);                // in flight across next compute
      MEMPIN();
      asm volatile("s_waitcnt vmcnt(8) lgkmcnt(0)" ::: "memory");  // retires exactly the 4 gl16 + ds_writes
    } else {
      asm volatile("s_waitcnt vmcnt(0) lgkmcnt(0)" ::: "memory");
    }
    SCHEDB();
    BARRIER();                             // tile staged everywhere
    SCHEDB();
    GCOMP();
  }

  const float bscale = z == 0 ? SCALE_Q : 1.0f;
  float bcol[4];
#pragma unroll
  for (int j = 0; j < 4; ++j) bcol[j] = bias[bn + wn * 64 + j * 16 + lr] * bscale;

  if (z < 2) {
    u16* C = z == 0 ? oq : ok;
#pragma unroll
    for (int i = 0; i < 4; ++i) {
      long m0 = bm + wm * 64 + i * 16 + lg * 4;
#pragma unroll
      for (int j = 0; j < 4; ++j) {
        long n = bn + wn * 64 + j * 16 + lr;
#pragma unroll
        for (int r = 0; r < 4; ++r)
          C[(m0 + r) * Nd + n] = f2bf(acc[i][j][r] + bcol[j]);
      }
    }
  } else {
    // V out, transposed vT[((b*16+h)*64+dv)][2048] with kv-axis pi-permutation
    // (bits 3<->2 of the within-16 s offset) so PV's B-frag is lane-local in k_attn.
    u16* C = ov;
    int lgp = ((lg & 1) << 1) | (lg >> 1);
#pragma unroll
    for (int i = 0; i < 4; ++i) {
      long m0 = bm + wm * 64 + i * 16 + lgp * 4;
      int b = (int)(m0 >> 11), s0 = (int)(m0 & 2047);
#pragma unroll
      for (int j = 0; j < 4; ++j) {
        int n = (int)(bn + wn * 64 + j * 16 + lr);
        int h = n >> 6, dv = n & 63;
        u32x2 cc;
        cc[0] = pk2(acc[i][j][0] + bcol[j], acc[i][j][1] + bcol[j]);
        cc[1] = pk2(acc[i][j][2] + bcol[j], acc[i][j][3] + bcol[j]);
        *(u32x2*)(C + (long)((b * 16 + h) * 64 + dv) * 2048 + s0) = cc;
      }
    }
  }
}

// ---------- output projection GEMM (bf16 in, f32 out), counted-vmcnt pipeline ----------
__global__ __launch_bounds__(256) void k_gemmo(const u16* __restrict__ A, const u16* __restrict__ Bt,
                                               const float* __restrict__ bias, float* __restrict__ C) {
  constexpr int Kd = 1024, Nd = 1024;
  __shared__ alignas(16) u16 As[2][128 * 64];
  __shared__ alignas(16) u16 Bs[2][128 * 64];
  const int t = threadIdx.x;
  const int lane = t & 63;
  const int w = t >> 6;
  const int wm = w >> 1, wn = w & 1;
  const int lr = lane & 15, lg = lane >> 4;
  const long bm = blockIdx.x * 128, bn = blockIdx.y * 128;
  const int r8 = lane >> 3, c8 = lane & 7;
  const int chunk = c8 ^ r8;

  f32x4 acc[4][4] = {};
  const u16* Ap = A + (bm + w * 8 + r8) * (long)Kd + chunk * 8;
  const u16* Bp = Bt + (bn + w * 8 + r8) * (long)Kd + chunk * 8;

  auto GSTAGE = [&](u16* Asb, u16* Bsb, int kt) {
#pragma unroll
    for (int p = 0; p < 4; ++p) {
      gl16(Ap + (long)p * 32 * Kd + kt, Asb + (p * 32 + w * 8) * 64);
      gl16(Bp + (long)p * 32 * Kd + kt, Bsb + (p * 32 + w * 8) * 64);
    }
  };
  auto GCOMP = [&](const u16* Asb, const u16* Bsb) {
#pragma unroll
    for (int ks = 0; ks < 2; ++ks) {
      s8v af[4], bf[4];
#pragma unroll
      for (int i = 0; i < 4; ++i) {
        int arow = wm * 64 + i * 16 + lr;
        af[i] = *(const s8v*)(Asb + arow * 64 + (((ks * 4 + lg) ^ (arow & 7)) * 8));
        int brow = wn * 64 + i * 16 + lr;
        bf[i] = *(const s8v*)(Bsb + brow * 64 + (((ks * 4 + lg) ^ (brow & 7)) * 8));
      }
#pragma unroll
      for (int i = 0; i < 4; ++i)
#pragma unroll
        for (int j = 0; j < 4; ++j)
          acc[i][j] = __builtin_amdgcn_mfma_f32_16x16x32_bf16(af[i], bf[j], acc[i][j], 0, 0, 0);
    }
  };

  GSTAGE(As[0], Bs[0], 0);
  for (int kt = 0; kt < 16; ++kt) {
    BARRIER();
    SCHEDB();
    if (kt < 15) {
      GSTAGE(As[(kt + 1) & 1], Bs[(kt + 1) & 1], (kt + 1) * 64);
      asm volatile("s_waitcnt vmcnt(8)" ::: "memory");
    } else {
      asm volatile("s_waitcnt vmcnt(0)" ::: "memory");
    }
    SCHEDB();
    BARRIER();
    SCHEDB();
    GCOMP(As[kt & 1], Bs[kt & 1]);
  }

  float bcol[4];
#pragma unroll
  for (int j = 0; j < 4; ++j) bcol[j] = bias[bn + wn * 64 + j * 16 + lr];
#pragma unroll
  for (int i = 0; i < 4; ++i) {
    long m0 = bm + wm * 64 + i * 16 + lg * 4;
#pragma unroll
    for (int j = 0; j < 4; ++j) {
      long n = bn + wn * 64 + j * 16 + lr;
#pragma unroll
      for (int r = 0; r < 4; ++r)
        C[(m0 + r) * Nd + n] = acc[i][j][r] + bcol[j];
    }
  }
}

// ---------- flash attention: R6 version (best measured, 91us) ----------
// 4 waves x 64 q, kb-split pipeline + sched_group_barrier; KVBLK=64; P in registers.
__global__ __launch_bounds__(256, 2) void k_attn(const u16* __restrict__ q, const u16* __restrict__ k,
                                                 const u16* __restrict__ vT, u16* __restrict__ o) {
  __shared__ alignas(16) u16 Ks[4][64 * 64];
  __shared__ alignas(16) u16 Vs[4][64 * 64];
  const int t = threadIdx.x;
  const int lane = t & 63;
  const int wv = t >> 6;                 // 0..3
  const int l5 = lane & 31, hi = lane >> 5;
  const int r8 = lane >> 3, c8 = lane & 7;
  const int rx = l5 & 7;

  // XCD-aware block swizzle: 8 qt-blocks of one (b,h) land on one XCD
  const int wg = blockIdx.x;                      // 0..511
  const int ob = (wg & 7) * 64 + (wg >> 3);       // bijective
  const int qt = ob & 7, h = (ob >> 3) & 15, b = ob >> 7;

  const int qrow0 = qt * 256 + wv * 64 + l5;      // q-block A
  const u16* qpA = q + ((long)(b * 2048 + qrow0) * 1024 + h * 64);
  const u16* qpB = qpA + 32 * 1024;               // q-block B (+32 rows)
  s8v qfA[4], qfB[4];
#pragma unroll
  for (int s = 0; s < 4; ++s) {
    qfA[s] = *(const s8v*)(qpA + s * 16 + hi * 8);
    qfB[s] = *(const s8v*)(qpB + s * 16 + hi * 8);
  }

  // pre-swizzled global sources (linear LDS dest; row&7 == r8)
  const u16* Kpp = k + (long)b * 2048 * 1024 + h * 64 + (long)r8 * 1024 + ((c8 ^ r8) * 8);
  const u16* Vpp = vT + (long)(b * 16 + h) * 131072 + (long)r8 * 2048 + ((c8 ^ r8) * 8);

  f32x16 accA0 = {}, accA1 = {}, accB0 = {}, accB1 = {};
  float lA = 0.f, lB = 0.f;

  int offs[4];
#pragma unroll
  for (int s = 0; s < 4; ++s) offs[s] = ((2 * s + hi) ^ rx) * 8;
  const int rb0 = l5 * 64, rb1 = rb0 + 2048;

  auto ASTAGE = [&](int buf, int kv) {            // wave wv stages rows [wv*16, wv*16+16)
#pragma unroll
    for (int r0 = 0; r0 < 2; ++r0) {
      int rowo = wv * 16 + r0 * 8;
      gl16(Kpp + ((long)kv + rowo) * 1024, &Ks[buf][rowo * 64]);
      gl16(Vpp + (long)rowo * 2048 + kv,   &Vs[buf][rowo * 64]);
    }
  };

  auto EXPPACK = [&](const f32x16& sv, PU& u0, PU& u1, float& l) {
#pragma unroll
    for (int r1 = 0; r1 < 4; ++r1) {
      float p0 = __builtin_amdgcn_exp2f(sv[4 * r1 + 0]);
      float p1 = __builtin_amdgcn_exp2f(sv[4 * r1 + 1]);
      float p2 = __builtin_amdgcn_exp2f(sv[4 * r1 + 2]);
      float p3 = __builtin_amdgcn_exp2f(sv[4 * r1 + 3]);
      l += (p0 + p1) + (p2 + p3);
      if (r1 < 2) {
        u0.w[(r1 & 1) * 2 + 0] = pk2(p0, p1);
        u0.w[(r1 & 1) * 2 + 1] = pk2(p2, p3);
      } else {
        u1.w[(r1 & 1) * 2 + 0] = pk2(p0, p1);
        u1.w[(r1 & 1) * 2 + 1] = pk2(p2, p3);
      }
    }
  };

  auto ATILE = [&](int buf) {
    const u16* Ksb = Ks[buf];
    const u16* Vsb = Vs[buf];
    PU paU[4], pbU[4];
    f32x16 sA0 = {}, sB0 = {}, sA1 = {}, sB1 = {};
    s8v kf0[4], kf1[4];
    // ---- P1: kf reads + QK kb0 ----
#pragma unroll
    for (int s = 0; s < 4; ++s) {
      kf0[s] = *(const s8v*)(Ksb + rb0 + offs[s]);
      kf1[s] = *(const s8v*)(Ksb + rb1 + offs[s]);
    }
#pragma unroll
    for (int s = 0; s < 4; ++s) {
      sA0 = __builtin_amdgcn_mfma_f32_32x32x16_bf16(kf0[s], qfA[s], sA0, 0, 0, 0);
      sB0 = __builtin_amdgcn_mfma_f32_32x32x16_bf16(kf0[s], qfB[s], sB0, 0, 0, 0);
    }
#pragma unroll
    for (int g = 0; g < 4; ++g) { SGB(0x100, 2); SGB(0x8, 2); }
    SCHEDB();
    // ---- P2: QK kb1 interleaved with exp/pack kb0 ----
#pragma unroll
    for (int s = 0; s < 4; ++s) {
      sA1 = __builtin_amdgcn_mfma_f32_32x32x16_bf16(kf1[s], qfA[s], sA1, 0, 0, 0);
      sB1 = __builtin_amdgcn_mfma_f32_32x32x16_bf16(kf1[s], qfB[s], sB1, 0, 0, 0);
    }
    EXPPACK(sA0, paU[0], paU[1], lA);
    EXPPACK(sB0, pbU[0], pbU[1], lB);
#pragma unroll
    for (int g = 0; g < 8; ++g) { SGB(0x8, 1); SGB(0x2, 9); }
    SCHEDB();
    // ---- P3: vf reads + PV (kb0 packs) interleaved with exp/pack kb1 ----
    s8v vf0[4], vf1[4];
#pragma unroll
    for (int s = 0; s < 4; ++s) {
      vf0[s] = *(const s8v*)(Vsb + rb0 + offs[s]);
      vf1[s] = *(const s8v*)(Vsb + rb1 + offs[s]);
    }
#pragma unroll
    for (int s2 = 0; s2 < 2; ++s2) {
      accA0 = __builtin_amdgcn_mfma_f32_32x32x16_bf16(vf0[s2], paU[s2].v, accA0, 0, 0, 0);
      accA1 = __builtin_amdgcn_mfma_f32_32x32x16_bf16(vf1[s2], paU[s2].v, accA1, 0, 0, 0);
      accB0 = __builtin_amdgcn_mfma_f32_32x32x16_bf16(vf0[s2], pbU[s2].v, accB0, 0, 0, 0);
      accB1 = __builtin_amdgcn_mfma_f32_32x32x16_bf16(vf1[s2], pbU[s2].v, accB1, 0, 0, 0);
    }
    EXPPACK(sA1, paU[2], paU[3], lA);
    EXPPACK(sB1, pbU[2], pbU[3], lB);
#pragma unroll
    for (int g = 0; g < 8; ++g) { SGB(0x100, 1); SGB(0x8, 1); SGB(0x2, 9); }
    SCHEDB();
    // ---- P4: PV (kb1 packs) ----
#pragma unroll
    for (int s2 = 2; s2 < 4; ++s2) {
      accA0 = __builtin_amdgcn_mfma_f32_32x32x16_bf16(vf0[s2], paU[s2].v, accA0, 0, 0, 0);
      accA1 = __builtin_amdgcn_mfma_f32_32x32x16_bf16(vf1[s2], paU[s2].v, accA1, 0, 0, 0);
      accB0 = __builtin_amdgcn_mfma_f32_32x32x16_bf16(vf0[s2], pbU[s2].v, accB0, 0, 0, 0);
      accB1 = __builtin_amdgcn_mfma_f32_32x32x16_bf16(vf1[s2], pbU[s2].v, accB1, 0, 0, 0);
    }
  };

  // ---- pipelined loop: 32 tiles, 4 buffers, prefetch depth 2 ----
  ASTAGE(0, 0);
  ASTAGE(1, 64);
  asm volatile("s_waitcnt vmcnt(4)" ::: "memory");
  SCHEDB();
  BARRIER();
  SCHEDB();
  for (int tt = 0; tt < 30; ++tt) {
    ASTAGE((tt + 2) & 3, (tt + 2) * 64);
    ATILE(tt & 3);
    asm volatile("s_waitcnt vmcnt(4) lgkmcnt(0)" ::: "memory");
    SCHEDB();
    BARRIER();
    SCHEDB();
  }
  ATILE(30 & 3);
  asm volatile("s_waitcnt vmcnt(0) lgkmcnt(0)" ::: "memory");
  SCHEDB();
  BARRIER();
  SCHEDB();
  ATILE(31 & 3);

  lA += __shfl_xor(lA, 32);
  lB += __shfl_xor(lB, 32);
  float iA = 1.0f / lA, iB = 1.0f / lB;
  u16* opA = o + ((long)(b * 2048 + qrow0) * 1024 + h * 64);
  u16* opB = opA + 32 * 1024;
#pragma unroll
  for (int kb = 0; kb < 2; ++kb) {
#pragma unroll
    for (int r1 = 0; r1 < 4; ++r1) {
      u32x2 ca, cb;
      float a0 = kb ? accA1[4 * r1 + 0] : accA0[4 * r1 + 0];
      float a1 = kb ? accA1[4 * r1 + 1] : accA0[4 * r1 + 1];
      float a2 = kb ? accA1[4 * r1 + 2] : accA0[4 * r1 + 2];
      float a3 = kb ? accA1[4 * r1 + 3] : accA0[4 * r1 + 3];
      ca[0] = pk2(a0 * iA, a1 * iA);
      ca[1] = pk2(a2 * iA, a3 * iA);
      *(u32x2*)(opA + kb * 32 + r1 * 8 + hi * 4) = ca;
      float b0v = kb ? accB1[4 * r1 + 0] : accB0[4 * r1 + 0];
      float b1v = kb ? accB1[4 * r1 + 1] : accB0[4 * r1 + 1];
      float b2v = kb ? accB1[4 * r1 + 2] : accB0[4 * r1 + 2];
      float b3v = kb ? accB1[4 * r1 + 3] : accB0[4 * r1 + 3];
      cb[0] = pk2(b0v * iB, b1v * iB);
      cb[1] = pk2(b2v * iB, b3v * iB);
      *(u32x2*)(opB + kb * 32 + r1 * 8 + hi * 4) = cb;
    }
  }
}

extern "C" void kernel_launch(void* const* d_in, const int* in_sizes, int n_in,
                              void* d_out, int out_size, void* d_ws, size_t ws_size,
                              hipStream_t stream) {
  const float* Q  = (const float*)d_in[0];
  const float* K  = (const float*)d_in[1];
  const float* V  = (const float*)d_in[2];
  const float* Wq = (const float*)d_in[3];
  const float* bq = (const float*)d_in[4];
  const float* Wk = (const float*)d_in[5];
  const float* bk = (const float*)d_in[6];
  const float* Wv = (const float*)d_in[7];
  const float* bvp = (const float*)d_in[8];
  const float* Wo = (const float*)d_in[9];
  const float* bo = (const float*)d_in[10];
  float* out = (float*)d_out;

  char* ws = (char*)d_ws;
  const size_t MB16 = (size_t)8192 * 1024 * 2;   // 16 MiB (one 8192x1024 bf16)
  u16* WqT = (u16*)(ws);
  u16* WkT = (u16*)(ws + ((size_t)2 << 20));
  u16* WvT = (u16*)(ws + ((size_t)4 << 20));
  u16* WoT = (u16*)(ws + ((size_t)6 << 20));
  u16* qws = (u16*)(ws + ((size_t)8 << 20));
  u16* kws = (u16*)(ws + ((size_t)8 << 20) + MB16);
  u16* vTs = (u16*)(ws + ((size_t)8 << 20) + 2 * MB16);
  u16* ows = (u16*)(ws + ((size_t)8 << 20) + 3 * MB16);

  k_convW_all<<<dim3(16, 16, 4), 256, 0, stream>>>(Wq, Wk, Wv, Wo, WqT, WkT, WvT, WoT);

  k_gemm3f<<<dim3(64, 8, 3), 256, 0, stream>>>(Q, K, V, WqT, WkT, WvT,
                                               bq, bk, bvp, qws, kws, vTs);

  k_attn<<<dim3(512), 256, 0, stream>>>(qws, kws, vTs, ows);

  k_gemmo<<<dim3(64, 8), 256, 0, stream>>>(ows, WoT, bo, out);
}